// Round 9
// baseline (90.891 us; speedup 1.0000x reference)
//
#include <hip/hip_runtime.h>
#include <hip/hip_bf16.h>

// Problem constants
#define WH 256          // 16*16
#define FEATSZ 4194304  // 8*2048*256
#define ROISZ  262144   // 8*16*2048

typedef short s16x4 __attribute__((ext_vector_type(4)));
typedef short s16x8 __attribute__((ext_vector_type(8)));
typedef float f32x4 __attribute__((ext_vector_type(4)));

__device__ inline void gld_lds16(void* lds, const void* g) {
  __builtin_amdgcn_global_load_lds(
      (const __attribute__((address_space(1))) unsigned int*)g,
      (__attribute__((address_space(3))) unsigned int*)lds,
      16, 0, 0);
}

__device__ inline unsigned short bf16u(float v) {
  __hip_bfloat16 h = __float2bfloat16(v);
  return *(unsigned short*)&h;
}

__device__ inline f32x4 ld4(const float* p) { return *(const f32x4*)p; }

// ---------------------------------------------------------------------------
// K1 (fused): three block-roles in one launch. Plain (cached) loads -- R8's
// nontemporal variant is reverted this round for A/B decomposition.
//  blocks [0,512):   pool (mean-of-4 temporal) + LDS transpose -> FpT[col][c]
//  blocks [512,576): conv_w fp32->bf16 cast
//  blocks [576,704): wbar (RoIAlign column-mean weights), 1 roi per block
// ---------------------------------------------------------------------------
__global__ __launch_bounds__(256) void fused_pre_kernel(
    const float* __restrict__ slow, const float* __restrict__ fast,
    const float* __restrict__ conv_w, const float* __restrict__ rois,
    __hip_bfloat16* __restrict__ FpT, __hip_bfloat16* __restrict__ Wb,
    float* __restrict__ wbar)
{
  __shared__ unsigned short tile[64][258];
  int blk = blockIdx.x;
  int tid = threadIdx.x;

  if (blk < 512) {
    // ---- pool + transpose ----
    int g = blk & 31;
    int t = (blk >> 5) & 1;
    int b = blk >> 6;
    int w = tid >> 6, lane = tid & 63;
    int wh4 = lane * 4;

    if (g < 16) {
      #pragma unroll 4
      for (int i = 0; i < 16; ++i) {
        int ch_l = i * 4 + w;
        int c = g * 64 + ch_l;
        const float* p = slow + ((size_t)((b * 1024 + c) * 8 + 4 * t)) * WH + wh4;
        f32x4 v0 = ld4(p);
        f32x4 v1 = ld4(p + WH);
        f32x4 v2 = ld4(p + 2 * WH);
        f32x4 v3 = ld4(p + 3 * WH);
        s16x4 o;
        o[0] = (short)bf16u(0.25f * (v0.x + v1.x + v2.x + v3.x));
        o[1] = (short)bf16u(0.25f * (v0.y + v1.y + v2.y + v3.y));
        o[2] = (short)bf16u(0.25f * (v0.z + v1.z + v2.z + v3.z));
        o[3] = (short)bf16u(0.25f * (v0.w + v1.w + v2.w + v3.w));
        *(s16x4*)&tile[ch_l][wh4] = o;
      }
    } else {
      int hi = (g - 16) >> 2;
      int cfb = ((g - 16) & 3) * 64;
      #pragma unroll 4
      for (int i = 0; i < 16; ++i) {
        int ch_l = i * 4 + w;
        int cf = cfb + ch_l;
        const float* p = fast + ((size_t)((b * 256 + cf) * 32 + 16 * t + hi)) * WH + wh4;
        f32x4 v0 = ld4(p);
        f32x4 v1 = ld4(p + 4 * WH);
        f32x4 v2 = ld4(p + 8 * WH);
        f32x4 v3 = ld4(p + 12 * WH);
        s16x4 o;
        o[0] = (short)bf16u(0.25f * (v0.x + v1.x + v2.x + v3.x));
        o[1] = (short)bf16u(0.25f * (v0.y + v1.y + v2.y + v3.y));
        o[2] = (short)bf16u(0.25f * (v0.z + v1.z + v2.z + v3.z));
        o[3] = (short)bf16u(0.25f * (v0.w + v1.w + v2.w + v3.w));
        *(s16x4*)&tile[ch_l][wh4] = o;
      }
    }
    __syncthreads();

    int c0 = (lane & 7) * 8;
    int col0 = (b * 2 + t) * 256;
    #pragma unroll
    for (int p = 0; p < 8; ++p) {
      int col_l = p * 32 + w * 8 + (lane >> 3);
      s16x8 o;
      #pragma unroll
      for (int j = 0; j < 8; ++j)
        o[j] = (short)tile[c0 + j][col_l];
      *(s16x8*)((char*)FpT + (size_t)(col0 + col_l) * 4096 + g * 128 + (lane & 7) * 16) = o;
    }
  } else if (blk < 576) {
    // ---- conv_w cast ----
    int tg = (blk - 512) * 256 + tid;
    #pragma unroll 4
    for (int j = 0; j < 32; ++j) {
      int idx = (j * 16384 + tg) * 4;
      f32x4 v = ld4(conv_w + idx);
      s16x4 o;
      o[0] = (short)bf16u(v.x);
      o[1] = (short)bf16u(v.y);
      o[2] = (short)bf16u(v.z);
      o[3] = (short)bf16u(v.w);
      *(s16x4*)(Wb + idx) = o;
    }
  } else {
    // ---- wbar (mmcv RoIAlign aligned=true, ratio=2, avg; /4 and /256) ----
    float* acc = (float*)tile;
    int n = blk - 576;
    acc[tid] = 0.f;
    __syncthreads();
    const float* r = rois + n * 5;
    float x1 = r[1] * (1.f / 16.f) - 0.5f;
    float y1 = r[2] * (1.f / 16.f) - 0.5f;
    float x2 = r[3] * (1.f / 16.f) - 0.5f;
    float y2 = r[4] * (1.f / 16.f) - 0.5f;
    float bw = (x2 - x1) / 16.f;
    float bh = (y2 - y1) / 16.f;
    int py = tid >> 4, px = tid & 15;
    #pragma unroll
    for (int sy = 0; sy < 2; ++sy) {
      #pragma unroll
      for (int sx = 0; sx < 2; ++sx) {
        float gy = (float)py + (sy + 0.5f) * 0.5f;
        float gx = (float)px + (sx + 0.5f) * 0.5f;
        float Yv = y1 + gy * bh;
        float Xv = x1 + gx * bw;
        if (Yv >= -1.f && Yv <= 16.f && Xv >= -1.f && Xv <= 16.f) {
          float y = fmaxf(Yv, 0.f);
          float x = fmaxf(Xv, 0.f);
          float y0f = floorf(y);
          float x0f = floorf(x);
          bool ye = y0f >= 15.f;
          bool xe = x0f >= 15.f;
          int y0 = ye ? 15 : (int)y0f;
          int y1i = ye ? 15 : y0 + 1;
          int x0 = xe ? 15 : (int)x0f;
          int x1i = xe ? 15 : x0 + 1;
          float ly = ye ? 0.f : (y - y0f);
          float lx = xe ? 0.f : (x - x0f);
          float hy = 1.f - ly, hx = 1.f - lx;
          atomicAdd(&acc[y0 * 16 + x0], hy * hx);
          atomicAdd(&acc[y0 * 16 + x1i], hy * lx);
          atomicAdd(&acc[y1i * 16 + x0], ly * hx);
          atomicAdd(&acc[y1i * 16 + x1i], ly * lx);
        }
      }
    }
    __syncthreads();
    wbar[n * 256 + tid] = acc[tid] * (1.f / 1024.f);
  }
}

// ---------------------------------------------------------------------------
// K3: GEMM  Y[o][col] = sum_c Wb[o][c] * FpT[col][c], M=1024 N=4096 K=2048.
// m97-class config: BM=BN=128 BK=64, 4 waves (2x2) each owning 64x64 out
// (4x4 frags, 32 MFMA/k-step/wave). gld_lds(16B) pre-swizzled source.
// grid (32,8) = 256 blocks. Epilogue: bf16 Y + f32 GN partials (8 slots/grp).
// ---------------------------------------------------------------------------
__global__ __launch_bounds__(256) void gemm_kernel(
    const __hip_bfloat16* __restrict__ Wb,   // [1024][2048]
    const __hip_bfloat16* __restrict__ FpT,  // [4096][2048]
    __hip_bfloat16* __restrict__ Yb,         // [1024][4096] bf16
    float2* __restrict__ partials)           // [128 groups][8 slots]
{
  __shared__ unsigned short lA[128 * 64];
  __shared__ unsigned short lB[128 * 64];
  const int tid = threadIdx.x;
  const int lane = tid & 63;
  const int wid = tid >> 6;
  const int wm = wid >> 1, wn = wid & 1;
  const int nb = blockIdx.x, mb = blockIdx.y;
  const int lr8 = lane >> 3;
  const int lk  = lane & 7;

  f32x4 acc[4][4] = {};

  for (int k0 = 0; k0 < 2048; k0 += 64) {
    __syncthreads();
    #pragma unroll
    for (int j = 0; j < 4; ++j) {
      int row = wid * 32 + j * 8 + lr8;
      int kslot = lk ^ (row & 7);
      const __hip_bfloat16* g = Wb + (size_t)(mb * 128 + row) * 2048 + k0 + kslot * 8;
      gld_lds16(&lA[(wid * 32 + j * 8) * 64], g);
    }
    #pragma unroll
    for (int j = 0; j < 4; ++j) {
      int row = wid * 32 + j * 8 + lr8;
      int kslot = lk ^ (row & 7);
      const __hip_bfloat16* g = FpT + (size_t)(nb * 128 + row) * 2048 + k0 + kslot * 8;
      gld_lds16(&lB[(wid * 32 + j * 8) * 64], g);
    }
    __syncthreads();

    #pragma unroll
    for (int s = 0; s < 2; ++s) {
      s16x8 af[4], bf[4];
      #pragma unroll
      for (int mi = 0; mi < 4; ++mi) {
        int row = wm * 64 + mi * 16 + (lane & 15);
        int kslot = (s * 4 + (lane >> 4)) ^ (row & 7);
        af[mi] = *(const s16x8*)((const char*)lA + (row << 7) + (kslot << 4));
      }
      #pragma unroll
      for (int ni = 0; ni < 4; ++ni) {
        int row = wn * 64 + ni * 16 + (lane & 15);
        int kslot = (s * 4 + (lane >> 4)) ^ (row & 7);
        bf[ni] = *(const s16x8*)((const char*)lB + (row << 7) + (kslot << 4));
      }
      #pragma unroll
      for (int mi = 0; mi < 4; ++mi)
        #pragma unroll
        for (int ni = 0; ni < 4; ++ni)
          acc[mi][ni] = __builtin_amdgcn_mfma_f32_16x16x32_bf16(af[mi], bf[ni], acc[mi][ni], 0, 0, 0);
    }
  }

  // C-write: C/D mapping col=lane&15, row=(lane>>4)*4+reg (m89/m91-verified)
  float s = 0.f, ss = 0.f;
  #pragma unroll
  for (int mi = 0; mi < 4; ++mi) {
    #pragma unroll
    for (int ni = 0; ni < 4; ++ni) {
      int col = nb * 128 + wn * 64 + ni * 16 + (lane & 15);
      int o0 = mb * 128 + wm * 64 + mi * 16 + (lane >> 4) * 4;
      #pragma unroll
      for (int r = 0; r < 4; ++r) {
        float v = acc[mi][ni][r];
        Yb[(size_t)(o0 + r) * 4096 + col] = __float2bfloat16(v);
        s += v;
        ss += v * v;
      }
    }
  }
  #pragma unroll
  for (int off = 32; off; off >>= 1) {
    s += __shfl_xor(s, off);
    ss += __shfl_xor(ss, off);
  }
  if (lane == 0) {
    int b = nb >> 2;                 // 4 nb-tiles per batch (128 cols each)
    int g = 2 * mb + wm;
    partials[(b * 16 + g) * 8 + (nb & 3) * 2 + wn] = make_float2(s, ss);
  }
}

// ---------------------------------------------------------------------------
// K4: GroupNorm normalize + ReLU + (c t) interleave into d_out.
// Reads bf16 Y (8 MB). grid 2048 = ((b*16+g)*16 + q), 256 thr; 8 elems/thr.
// ---------------------------------------------------------------------------
__global__ __launch_bounds__(256) void gn_kernel(
    const __hip_bfloat16* __restrict__ Yb, const float2* __restrict__ partials,
    const float* __restrict__ gamma, const float* __restrict__ beta,
    float* __restrict__ out)
{
  int blk = blockIdx.x;
  int q = blk & 15;
  int bg = blk >> 4;            // b*16 + g
  int b = bg >> 4, g = bg & 15;
  const float2* pp = partials + bg * 8;
  float S = 0.f, SS = 0.f;
  #pragma unroll
  for (int j = 0; j < 8; ++j) { float2 v = pp[j]; S += v.x; SS += v.y; }
  float mu = S * (1.f / 32768.f);
  float var = SS * (1.f / 32768.f) - mu * mu;
  float rstd = rsqrtf(var + 1e-5f);

  int tid = threadIdx.x;
  int o_l = q * 4 + (tid >> 6);
  int o = g * 64 + o_l;
  int colpos = (tid & 63) * 8;
  const __hip_bfloat16* src = Yb + (size_t)o * 4096 + b * 512 + colpos;
  float ga = gamma[o] * rstd, be = beta[o] - mu * rstd * gamma[o];
  int t = colpos >> 8, wh = colpos & 255;
  float* dst = out + ((size_t)(b * 2048 + o * 2 + t)) * 256 + wh;
  s16x8 yv = *(const s16x8*)src;
  #pragma unroll
  for (int j = 0; j < 2; ++j) {
    float4 r;
    r.x = fmaxf(__uint_as_float((unsigned)(unsigned short)yv[j * 4 + 0] << 16) * ga + be, 0.f);
    r.y = fmaxf(__uint_as_float((unsigned)(unsigned short)yv[j * 4 + 1] << 16) * ga + be, 0.f);
    r.z = fmaxf(__uint_as_float((unsigned)(unsigned short)yv[j * 4 + 2] << 16) * ga + be, 0.f);
    r.w = fmaxf(__uint_as_float((unsigned)(unsigned short)yv[j * 4 + 3] << 16) * ga + be, 0.f);
    *(float4*)(dst + j * 4) = r;
  }
}

// ---------------------------------------------------------------------------
// K6: roi_feat[n][c] = sum_q wbar[n][q] feat[b][c][q];
//     roi_pos [n][c] = sum_q wbar[n][q] pos[c][q].
// ---------------------------------------------------------------------------
__global__ __launch_bounds__(256) void roi_kernel(
    const float* __restrict__ feat, const float* __restrict__ pos,
    const float* __restrict__ wbar, float* __restrict__ out)
{
  __shared__ float wl[16][256];
  __shared__ float sF[2][16][128];
  __shared__ float sP[2][16][128];
  int b = blockIdx.x >> 4;
  int chunk = blockIdx.x & 15;
  int tid = threadIdx.x;
  #pragma unroll
  for (int rr = 0; rr < 16; ++rr)
    wl[rr][tid] = wbar[(b * 16 + rr) * 256 + tid];
  __syncthreads();
  int ch_l = tid & 127;
  int half = tid >> 7;
  int ch = chunk * 128 + ch_l;
  const float* fb = feat + ((size_t)(b * 2048 + ch)) * 256 + half * 128;
  const float* pb = pos + (size_t)ch * 256 + half * 128;
  float accF[16] = {0.f}, accP[16] = {0.f};
  for (int q0 = 0; q0 < 128; q0 += 4) {
    float4 vf = *(const float4*)(fb + q0);
    float4 vp = *(const float4*)(pb + q0);
    int q = half * 128 + q0;
    #pragma unroll
    for (int rr = 0; rr < 16; ++rr) {
      float4 w = *(const float4*)&wl[rr][q];
      accF[rr] += w.x * vf.x + w.y * vf.y + w.z * vf.z + w.w * vf.w;
      accP[rr] += w.x * vp.x + w.y * vp.y + w.z * vp.z + w.w * vp.w;
    }
  }
  #pragma unroll
  for (int rr = 0; rr < 16; ++rr) {
    sF[half][rr][ch_l] = accF[rr];
    sP[half][rr][ch_l] = accP[rr];
  }
  __syncthreads();
  if (half == 0) {
    #pragma unroll
    for (int rr = 0; rr < 16; ++rr) {
      float vF = sF[0][rr][ch_l] + sF[1][rr][ch_l];
      float vP = sP[0][rr][ch_l] + sP[1][rr][ch_l];
      out[FEATSZ + (size_t)(b * 16 + rr) * 2048 + ch] = vF;
      out[FEATSZ + ROISZ + (size_t)(b * 16 + rr) * 2048 + ch] = vP;
    }
  }
}

// ---------------------------------------------------------------------------
extern "C" void kernel_launch(void* const* d_in, const int* in_sizes, int n_in,
                              void* d_out, int out_size, void* d_ws, size_t ws_size,
                              hipStream_t stream)
{
  (void)in_sizes; (void)n_in; (void)out_size; (void)ws_size;
  const float* slow   = (const float*)d_in[0];
  const float* fast   = (const float*)d_in[1];
  const float* rois   = (const float*)d_in[2];
  const float* pos    = (const float*)d_in[3];
  const float* conv_w = (const float*)d_in[4];
  const float* gamma  = (const float*)d_in[5];
  const float* beta   = (const float*)d_in[6];
  float* out = (float*)d_out;
  char* ws = (char*)d_ws;

  // Workspace (~28.15 MB):
  //   [0, 16M)        FpT [4096][2048] bf16
  //   [16M, 24M)      Yb  [1024][4096] bf16
  //   [24M, 28M)      Wb  [1024][2048] bf16
  //   [28M, +128K)    wbar [128][256] f32
  //   [28M+128K,+8K)  partials [128][8] float2
  __hip_bfloat16* FpT = (__hip_bfloat16*)(ws);
  __hip_bfloat16* Yb  = (__hip_bfloat16*)(ws + (16u << 20));
  __hip_bfloat16* Wb  = (__hip_bfloat16*)(ws + (24u << 20));
  float* wbar         = (float*)(ws + (28u << 20));
  float2* partials    = (float2*)(ws + (28u << 20) + (128u << 10));

  fused_pre_kernel<<<dim3(704), dim3(256), 0, stream>>>(
      slow, fast, conv_w, rois, FpT, Wb, wbar);
  gemm_kernel<<<dim3(32, 8), dim3(256), 0, stream>>>(Wb, FpT, Yb, partials);
  gn_kernel<<<dim3(2048), dim3(256), 0, stream>>>(Yb, partials, gamma, beta, out);
  roi_kernel<<<dim3(128), dim3(256), 0, stream>>>(out, pos, wbar, out);
}

// Round 10
// 88.069 us; speedup vs baseline: 1.0320x; 1.0320x over previous
//
#include <hip/hip_runtime.h>
#include <hip/hip_bf16.h>

// Problem constants
#define WH 256          // 16*16
#define FEATSZ 4194304  // 8*2048*256
#define ROISZ  262144   // 8*16*2048

typedef short s16x4 __attribute__((ext_vector_type(4)));
typedef short s16x8 __attribute__((ext_vector_type(8)));
typedef float f32x4 __attribute__((ext_vector_type(4)));

__device__ inline void gld_lds16(void* lds, const void* g) {
  __builtin_amdgcn_global_load_lds(
      (const __attribute__((address_space(1))) unsigned int*)g,
      (__attribute__((address_space(3))) unsigned int*)lds,
      16, 0, 0);
}

__device__ inline unsigned short bf16u(float v) {
  __hip_bfloat16 h = __float2bfloat16(v);
  return *(unsigned short*)&h;
}

// nontemporal 16B load (ext-vector pointee required by the builtin)
__device__ inline f32x4 ntload4(const float* p) {
  return __builtin_nontemporal_load((const f32x4*)p);
}

// ---------------------------------------------------------------------------
// K1 (fused): three block-roles in one launch. Input reads NON-TEMPORAL
// (single variable changed vs the 81.4us R5 baseline).
//  blocks [0,512):   pool (mean-of-4 temporal) + LDS transpose -> FpT[col][c]
//  blocks [512,576): conv_w fp32->bf16 cast
//  blocks [576,704): wbar (RoIAlign column-mean weights), 1 roi per block
// ---------------------------------------------------------------------------
__global__ __launch_bounds__(256) void fused_pre_kernel(
    const float* __restrict__ slow, const float* __restrict__ fast,
    const float* __restrict__ conv_w, const float* __restrict__ rois,
    __hip_bfloat16* __restrict__ FpT, __hip_bfloat16* __restrict__ Wb,
    float* __restrict__ wbar)
{
  __shared__ unsigned short tile[64][258];
  int blk = blockIdx.x;
  int tid = threadIdx.x;

  if (blk < 512) {
    // ---- pool + transpose ----
    int g = blk & 31;
    int t = (blk >> 5) & 1;
    int b = blk >> 6;
    int w = tid >> 6, lane = tid & 63;
    int wh4 = lane * 4;

    if (g < 16) {
      #pragma unroll 4
      for (int i = 0; i < 16; ++i) {
        int ch_l = i * 4 + w;
        int c = g * 64 + ch_l;
        const float* p = slow + ((size_t)((b * 1024 + c) * 8 + 4 * t)) * WH + wh4;
        f32x4 v0 = ntload4(p);
        f32x4 v1 = ntload4(p + WH);
        f32x4 v2 = ntload4(p + 2 * WH);
        f32x4 v3 = ntload4(p + 3 * WH);
        s16x4 o;
        o[0] = (short)bf16u(0.25f * (v0.x + v1.x + v2.x + v3.x));
        o[1] = (short)bf16u(0.25f * (v0.y + v1.y + v2.y + v3.y));
        o[2] = (short)bf16u(0.25f * (v0.z + v1.z + v2.z + v3.z));
        o[3] = (short)bf16u(0.25f * (v0.w + v1.w + v2.w + v3.w));
        *(s16x4*)&tile[ch_l][wh4] = o;
      }
    } else {
      int hi = (g - 16) >> 2;
      int cfb = ((g - 16) & 3) * 64;
      #pragma unroll 4
      for (int i = 0; i < 16; ++i) {
        int ch_l = i * 4 + w;
        int cf = cfb + ch_l;
        const float* p = fast + ((size_t)((b * 256 + cf) * 32 + 16 * t + hi)) * WH + wh4;
        f32x4 v0 = ntload4(p);
        f32x4 v1 = ntload4(p + 4 * WH);
        f32x4 v2 = ntload4(p + 8 * WH);
        f32x4 v3 = ntload4(p + 12 * WH);
        s16x4 o;
        o[0] = (short)bf16u(0.25f * (v0.x + v1.x + v2.x + v3.x));
        o[1] = (short)bf16u(0.25f * (v0.y + v1.y + v2.y + v3.y));
        o[2] = (short)bf16u(0.25f * (v0.z + v1.z + v2.z + v3.z));
        o[3] = (short)bf16u(0.25f * (v0.w + v1.w + v2.w + v3.w));
        *(s16x4*)&tile[ch_l][wh4] = o;
      }
    }
    __syncthreads();

    int c0 = (lane & 7) * 8;
    int col0 = (b * 2 + t) * 256;
    #pragma unroll
    for (int p = 0; p < 8; ++p) {
      int col_l = p * 32 + w * 8 + (lane >> 3);
      s16x8 o;
      #pragma unroll
      for (int j = 0; j < 8; ++j)
        o[j] = (short)tile[c0 + j][col_l];
      *(s16x8*)((char*)FpT + (size_t)(col0 + col_l) * 4096 + g * 128 + (lane & 7) * 16) = o;
    }
  } else if (blk < 576) {
    // ---- conv_w cast ----
    int tg = (blk - 512) * 256 + tid;
    #pragma unroll 4
    for (int j = 0; j < 32; ++j) {
      int idx = (j * 16384 + tg) * 4;
      f32x4 v = ntload4(conv_w + idx);
      s16x4 o;
      o[0] = (short)bf16u(v.x);
      o[1] = (short)bf16u(v.y);
      o[2] = (short)bf16u(v.z);
      o[3] = (short)bf16u(v.w);
      *(s16x4*)(Wb + idx) = o;
    }
  } else {
    // ---- wbar (mmcv RoIAlign aligned=true, ratio=2, avg; /4 and /256) ----
    float* acc = (float*)tile;
    int n = blk - 576;
    acc[tid] = 0.f;
    __syncthreads();
    const float* r = rois + n * 5;
    float x1 = r[1] * (1.f / 16.f) - 0.5f;
    float y1 = r[2] * (1.f / 16.f) - 0.5f;
    float x2 = r[3] * (1.f / 16.f) - 0.5f;
    float y2 = r[4] * (1.f / 16.f) - 0.5f;
    float bw = (x2 - x1) / 16.f;
    float bh = (y2 - y1) / 16.f;
    int py = tid >> 4, px = tid & 15;
    #pragma unroll
    for (int sy = 0; sy < 2; ++sy) {
      #pragma unroll
      for (int sx = 0; sx < 2; ++sx) {
        float gy = (float)py + (sy + 0.5f) * 0.5f;
        float gx = (float)px + (sx + 0.5f) * 0.5f;
        float Yv = y1 + gy * bh;
        float Xv = x1 + gx * bw;
        if (Yv >= -1.f && Yv <= 16.f && Xv >= -1.f && Xv <= 16.f) {
          float y = fmaxf(Yv, 0.f);
          float x = fmaxf(Xv, 0.f);
          float y0f = floorf(y);
          float x0f = floorf(x);
          bool ye = y0f >= 15.f;
          bool xe = x0f >= 15.f;
          int y0 = ye ? 15 : (int)y0f;
          int y1i = ye ? 15 : y0 + 1;
          int x0 = xe ? 15 : (int)x0f;
          int x1i = xe ? 15 : x0 + 1;
          float ly = ye ? 0.f : (y - y0f);
          float lx = xe ? 0.f : (x - x0f);
          float hy = 1.f - ly, hx = 1.f - lx;
          atomicAdd(&acc[y0 * 16 + x0], hy * hx);
          atomicAdd(&acc[y0 * 16 + x1i], hy * lx);
          atomicAdd(&acc[y1i * 16 + x0], ly * hx);
          atomicAdd(&acc[y1i * 16 + x1i], ly * lx);
        }
      }
    }
    __syncthreads();
    wbar[n * 256 + tid] = acc[tid] * (1.f / 1024.f);
  }
}

// ---------------------------------------------------------------------------
// K3: GEMM  Y[o][col] = sum_c Wb[o][c] * FpT[col][c], M=1024 N=4096 K=2048.
// BM=128 BN=64 BK=64, 4 waves (2x2), gld_lds(16B) pre-swizzled src.
// 512 blocks = 2/CU (R9 showed 256 blocks/1-per-CU regresses: no wave
// overlap across the barrier drain). f32 Y restored (R5-identical).
// ---------------------------------------------------------------------------
__global__ __launch_bounds__(256) void gemm_kernel(
    const __hip_bfloat16* __restrict__ Wb,   // [1024][2048]
    const __hip_bfloat16* __restrict__ FpT,  // [4096][2048]
    float* __restrict__ Y,                   // [1024][4096]
    float2* __restrict__ partials)           // [128 groups][16 slots]
{
  __shared__ unsigned short lA[128 * 64];
  __shared__ unsigned short lB[64 * 64];
  const int tid = threadIdx.x;
  const int lane = tid & 63;
  const int wid = tid >> 6;
  const int wm = wid >> 1, wn = wid & 1;
  const int nb = blockIdx.x, mb = blockIdx.y;
  const int lr8 = lane >> 3;
  const int lk  = lane & 7;

  f32x4 acc[4][2] = {};

  for (int k0 = 0; k0 < 2048; k0 += 64) {
    __syncthreads();
    #pragma unroll
    for (int j = 0; j < 4; ++j) {
      int row = wid * 32 + j * 8 + lr8;
      int kslot = lk ^ (row & 7);
      const __hip_bfloat16* g = Wb + (size_t)(mb * 128 + row) * 2048 + k0 + kslot * 8;
      gld_lds16(&lA[(wid * 32 + j * 8) * 64], g);
    }
    #pragma unroll
    for (int j = 0; j < 2; ++j) {
      int row = wid * 16 + j * 8 + lr8;
      int kslot = lk ^ (row & 7);
      const __hip_bfloat16* g = FpT + (size_t)(nb * 64 + row) * 2048 + k0 + kslot * 8;
      gld_lds16(&lB[(wid * 16 + j * 8) * 64], g);
    }
    __syncthreads();

    #pragma unroll
    for (int s = 0; s < 2; ++s) {
      s16x8 af[4], bf[2];
      #pragma unroll
      for (int mi = 0; mi < 4; ++mi) {
        int row = wm * 64 + mi * 16 + (lane & 15);
        int kslot = (s * 4 + (lane >> 4)) ^ (row & 7);
        af[mi] = *(const s16x8*)((const char*)lA + (row << 7) + (kslot << 4));
      }
      #pragma unroll
      for (int ni = 0; ni < 2; ++ni) {
        int row = wn * 32 + ni * 16 + (lane & 15);
        int kslot = (s * 4 + (lane >> 4)) ^ (row & 7);
        bf[ni] = *(const s16x8*)((const char*)lB + (row << 7) + (kslot << 4));
      }
      #pragma unroll
      for (int mi = 0; mi < 4; ++mi)
        #pragma unroll
        for (int ni = 0; ni < 2; ++ni)
          acc[mi][ni] = __builtin_amdgcn_mfma_f32_16x16x32_bf16(af[mi], bf[ni], acc[mi][ni], 0, 0, 0);
    }
  }

  // C-write: C/D mapping col=lane&15, row=(lane>>4)*4+reg (m89/m91-verified)
  float s = 0.f, ss = 0.f;
  #pragma unroll
  for (int mi = 0; mi < 4; ++mi) {
    #pragma unroll
    for (int ni = 0; ni < 2; ++ni) {
      int col = nb * 64 + wn * 32 + ni * 16 + (lane & 15);
      int o0 = mb * 128 + wm * 64 + mi * 16 + (lane >> 4) * 4;
      #pragma unroll
      for (int r = 0; r < 4; ++r) {
        float v = acc[mi][ni][r];
        Y[(size_t)(o0 + r) * 4096 + col] = v;
        s += v;
        ss += v * v;
      }
    }
  }
  #pragma unroll
  for (int off = 32; off; off >>= 1) {
    s += __shfl_xor(s, off);
    ss += __shfl_xor(ss, off);
  }
  if (lane == 0) {
    int b = nb >> 3;
    int g = 2 * mb + wm;
    partials[(b * 16 + g) * 16 + (nb & 7) * 2 + wn] = make_float2(s, ss);
  }
}

// ---------------------------------------------------------------------------
// K4: GroupNorm normalize + ReLU + (c t) interleave into d_out.
// grid 2048 = ((b*16+g)*16 + q), 256 thr; each thread 8 elems.
// ---------------------------------------------------------------------------
__global__ __launch_bounds__(256) void gn_kernel(
    const float* __restrict__ Y, const float2* __restrict__ partials,
    const float* __restrict__ gamma, const float* __restrict__ beta,
    float* __restrict__ out)
{
  int blk = blockIdx.x;
  int q = blk & 15;
  int bg = blk >> 4;            // b*16 + g
  int b = bg >> 4, g = bg & 15;
  const float2* pp = partials + bg * 16;
  float S = 0.f, SS = 0.f;
  #pragma unroll
  for (int j = 0; j < 16; ++j) { float2 v = pp[j]; S += v.x; SS += v.y; }
  float mu = S * (1.f / 32768.f);
  float var = SS * (1.f / 32768.f) - mu * mu;
  float rstd = rsqrtf(var + 1e-5f);

  int tid = threadIdx.x;
  int o_l = q * 4 + (tid >> 6);
  int o = g * 64 + o_l;
  int colpos = (tid & 63) * 8;
  const float* src = Y + (size_t)o * 4096 + b * 512 + colpos;
  float ga = gamma[o] * rstd, be = beta[o] - mu * rstd * gamma[o];
  int t = colpos >> 8, wh = colpos & 255;
  float* dst = out + ((size_t)(b * 2048 + o * 2 + t)) * 256 + wh;
  #pragma unroll
  for (int j = 0; j < 2; ++j) {
    float4 v = *(const float4*)(src + j * 4);
    float4 r;
    r.x = fmaxf(v.x * ga + be, 0.f);
    r.y = fmaxf(v.y * ga + be, 0.f);
    r.z = fmaxf(v.z * ga + be, 0.f);
    r.w = fmaxf(v.w * ga + be, 0.f);
    *(float4*)(dst + j * 4) = r;
  }
}

// ---------------------------------------------------------------------------
// K6: roi_feat[n][c] = sum_q wbar[n][q] feat[b][c][q];
//     roi_pos [n][c] = sum_q wbar[n][q] pos[c][q].
// ---------------------------------------------------------------------------
__global__ __launch_bounds__(256) void roi_kernel(
    const float* __restrict__ feat, const float* __restrict__ pos,
    const float* __restrict__ wbar, float* __restrict__ out)
{
  __shared__ float wl[16][256];
  __shared__ float sF[2][16][128];
  __shared__ float sP[2][16][128];
  int b = blockIdx.x >> 4;
  int chunk = blockIdx.x & 15;
  int tid = threadIdx.x;
  #pragma unroll
  for (int rr = 0; rr < 16; ++rr)
    wl[rr][tid] = wbar[(b * 16 + rr) * 256 + tid];
  __syncthreads();
  int ch_l = tid & 127;
  int half = tid >> 7;
  int ch = chunk * 128 + ch_l;
  const float* fb = feat + ((size_t)(b * 2048 + ch)) * 256 + half * 128;
  const float* pb = pos + (size_t)ch * 256 + half * 128;
  float accF[16] = {0.f}, accP[16] = {0.f};
  for (int q0 = 0; q0 < 128; q0 += 4) {
    float4 vf = *(const float4*)(fb + q0);
    float4 vp = *(const float4*)(pb + q0);
    int q = half * 128 + q0;
    #pragma unroll
    for (int rr = 0; rr < 16; ++rr) {
      float4 w = *(const float4*)&wl[rr][q];
      accF[rr] += w.x * vf.x + w.y * vf.y + w.z * vf.z + w.w * vf.w;
      accP[rr] += w.x * vp.x + w.y * vp.y + w.z * vp.z + w.w * vp.w;
    }
  }
  #pragma unroll
  for (int rr = 0; rr < 16; ++rr) {
    sF[half][rr][ch_l] = accF[rr];
    sP[half][rr][ch_l] = accP[rr];
  }
  __syncthreads();
  if (half == 0) {
    #pragma unroll
    for (int rr = 0; rr < 16; ++rr) {
      float vF = sF[0][rr][ch_l] + sF[1][rr][ch_l];
      float vP = sP[0][rr][ch_l] + sP[1][rr][ch_l];
      out[FEATSZ + (size_t)(b * 16 + rr) * 2048 + ch] = vF;
      out[FEATSZ + ROISZ + (size_t)(b * 16 + rr) * 2048 + ch] = vP;
    }
  }
}

// ---------------------------------------------------------------------------
extern "C" void kernel_launch(void* const* d_in, const int* in_sizes, int n_in,
                              void* d_out, int out_size, void* d_ws, size_t ws_size,
                              hipStream_t stream)
{
  (void)in_sizes; (void)n_in; (void)out_size; (void)ws_size;
  const float* slow   = (const float*)d_in[0];
  const float* fast   = (const float*)d_in[1];
  const float* rois   = (const float*)d_in[2];
  const float* pos    = (const float*)d_in[3];
  const float* conv_w = (const float*)d_in[4];
  const float* gamma  = (const float*)d_in[5];
  const float* beta   = (const float*)d_in[6];
  float* out = (float*)d_out;
  char* ws = (char*)d_ws;

  // Workspace (R5-identical, ~36.1 MB):
  //   [0, 16M)     FpT [4096][2048] bf16
  //   [16M, 32M)   Y   [1024][4096] f32
  //   [32M, 36M)   Wb  [1024][2048] bf16
  //   [36M,+128K)  wbar [128][256] f32
  // partials [128][16] float2 in d_out's roi_feat region (gemm writes ->
  // gn reads -> roi_kernel overwrites last).
  __hip_bfloat16* FpT = (__hip_bfloat16*)(ws);
  float*  Y           = (float*)(ws + (16u << 20));
  __hip_bfloat16* Wb  = (__hip_bfloat16*)(ws + (32u << 20));
  float*  wbar        = (float*)(ws + (36u << 20));
  float2* partials    = (float2*)(out + FEATSZ);

  fused_pre_kernel<<<dim3(704), dim3(256), 0, stream>>>(
      slow, fast, conv_w, rois, FpT, Wb, wbar);
  gemm_kernel<<<dim3(64, 8), dim3(256), 0, stream>>>(Wb, FpT, Y, partials);
  gn_kernel<<<dim3(2048), dim3(256), 0, stream>>>(Y, partials, gamma, beta, out);
  roi_kernel<<<dim3(128), dim3(256), 0, stream>>>(out, pos, wbar, out);
}

// Round 11
// 77.605 us; speedup vs baseline: 1.1712x; 1.1348x over previous
//
#include <hip/hip_runtime.h>
#include <hip/hip_bf16.h>

// Problem constants
#define WH 256          // 16*16
#define FEATSZ 4194304  // 8*2048*256
#define ROISZ  262144   // 8*16*2048

typedef short s16x4 __attribute__((ext_vector_type(4)));
typedef short s16x8 __attribute__((ext_vector_type(8)));
typedef float f32x4 __attribute__((ext_vector_type(4)));

__device__ inline void gld_lds16(void* lds, const void* g) {
  __builtin_amdgcn_global_load_lds(
      (const __attribute__((address_space(1))) unsigned int*)g,
      (__attribute__((address_space(3))) unsigned int*)lds,
      16, 0, 0);
}

__device__ inline unsigned short bf16u(float v) {
  __hip_bfloat16 h = __float2bfloat16(v);
  return *(unsigned short*)&h;
}

__device__ inline f32x4 ld4(const float* p) { return *(const f32x4*)p; }

// ---------------------------------------------------------------------------
// K1 (fused): three block-roles in one launch. Plain cached loads (nt loads
// measured as net-loss in the L3-warm timed regime, R10).
//  blocks [0,512):   pool (mean-of-4 temporal) + LDS transpose -> FpT[col][c]
//  blocks [512,576): conv_w fp32->bf16 cast
//  blocks [576,704): wbar (RoIAlign column-mean weights), 1 roi per block
// At the measured L3->L2 fill wall (~2.9 TB/s): ~55 us floor for 155 MB.
// ---------------------------------------------------------------------------
__global__ __launch_bounds__(256) void fused_pre_kernel(
    const float* __restrict__ slow, const float* __restrict__ fast,
    const float* __restrict__ conv_w, const float* __restrict__ rois,
    __hip_bfloat16* __restrict__ FpT, __hip_bfloat16* __restrict__ Wb,
    float* __restrict__ wbar)
{
  __shared__ unsigned short tile[64][258];
  int blk = blockIdx.x;
  int tid = threadIdx.x;

  if (blk < 512) {
    // ---- pool + transpose ----
    int g = blk & 31;
    int t = (blk >> 5) & 1;
    int b = blk >> 6;
    int w = tid >> 6, lane = tid & 63;
    int wh4 = lane * 4;

    if (g < 16) {
      #pragma unroll 4
      for (int i = 0; i < 16; ++i) {
        int ch_l = i * 4 + w;
        int c = g * 64 + ch_l;
        const float* p = slow + ((size_t)((b * 1024 + c) * 8 + 4 * t)) * WH + wh4;
        f32x4 v0 = ld4(p);
        f32x4 v1 = ld4(p + WH);
        f32x4 v2 = ld4(p + 2 * WH);
        f32x4 v3 = ld4(p + 3 * WH);
        s16x4 o;
        o[0] = (short)bf16u(0.25f * (v0.x + v1.x + v2.x + v3.x));
        o[1] = (short)bf16u(0.25f * (v0.y + v1.y + v2.y + v3.y));
        o[2] = (short)bf16u(0.25f * (v0.z + v1.z + v2.z + v3.z));
        o[3] = (short)bf16u(0.25f * (v0.w + v1.w + v2.w + v3.w));
        *(s16x4*)&tile[ch_l][wh4] = o;
      }
    } else {
      int hi = (g - 16) >> 2;
      int cfb = ((g - 16) & 3) * 64;
      #pragma unroll 4
      for (int i = 0; i < 16; ++i) {
        int ch_l = i * 4 + w;
        int cf = cfb + ch_l;
        const float* p = fast + ((size_t)((b * 256 + cf) * 32 + 16 * t + hi)) * WH + wh4;
        f32x4 v0 = ld4(p);
        f32x4 v1 = ld4(p + 4 * WH);
        f32x4 v2 = ld4(p + 8 * WH);
        f32x4 v3 = ld4(p + 12 * WH);
        s16x4 o;
        o[0] = (short)bf16u(0.25f * (v0.x + v1.x + v2.x + v3.x));
        o[1] = (short)bf16u(0.25f * (v0.y + v1.y + v2.y + v3.y));
        o[2] = (short)bf16u(0.25f * (v0.z + v1.z + v2.z + v3.z));
        o[3] = (short)bf16u(0.25f * (v0.w + v1.w + v2.w + v3.w));
        *(s16x4*)&tile[ch_l][wh4] = o;
      }
    }
    __syncthreads();

    int c0 = (lane & 7) * 8;
    int col0 = (b * 2 + t) * 256;
    #pragma unroll
    for (int p = 0; p < 8; ++p) {
      int col_l = p * 32 + w * 8 + (lane >> 3);
      s16x8 o;
      #pragma unroll
      for (int j = 0; j < 8; ++j)
        o[j] = (short)tile[c0 + j][col_l];
      *(s16x8*)((char*)FpT + (size_t)(col0 + col_l) * 4096 + g * 128 + (lane & 7) * 16) = o;
    }
  } else if (blk < 576) {
    // ---- conv_w cast ----
    int tg = (blk - 512) * 256 + tid;
    #pragma unroll 4
    for (int j = 0; j < 32; ++j) {
      int idx = (j * 16384 + tg) * 4;
      f32x4 v = ld4(conv_w + idx);
      s16x4 o;
      o[0] = (short)bf16u(v.x);
      o[1] = (short)bf16u(v.y);
      o[2] = (short)bf16u(v.z);
      o[3] = (short)bf16u(v.w);
      *(s16x4*)(Wb + idx) = o;
    }
  } else {
    // ---- wbar (mmcv RoIAlign aligned=true, ratio=2, avg; /4 and /256) ----
    float* acc = (float*)tile;
    int n = blk - 576;
    acc[tid] = 0.f;
    __syncthreads();
    const float* r = rois + n * 5;
    float x1 = r[1] * (1.f / 16.f) - 0.5f;
    float y1 = r[2] * (1.f / 16.f) - 0.5f;
    float x2 = r[3] * (1.f / 16.f) - 0.5f;
    float y2 = r[4] * (1.f / 16.f) - 0.5f;
    float bw = (x2 - x1) / 16.f;
    float bh = (y2 - y1) / 16.f;
    int py = tid >> 4, px = tid & 15;
    #pragma unroll
    for (int sy = 0; sy < 2; ++sy) {
      #pragma unroll
      for (int sx = 0; sx < 2; ++sx) {
        float gy = (float)py + (sy + 0.5f) * 0.5f;
        float gx = (float)px + (sx + 0.5f) * 0.5f;
        float Yv = y1 + gy * bh;
        float Xv = x1 + gx * bw;
        if (Yv >= -1.f && Yv <= 16.f && Xv >= -1.f && Xv <= 16.f) {
          float y = fmaxf(Yv, 0.f);
          float x = fmaxf(Xv, 0.f);
          float y0f = floorf(y);
          float x0f = floorf(x);
          bool ye = y0f >= 15.f;
          bool xe = x0f >= 15.f;
          int y0 = ye ? 15 : (int)y0f;
          int y1i = ye ? 15 : y0 + 1;
          int x0 = xe ? 15 : (int)x0f;
          int x1i = xe ? 15 : x0 + 1;
          float ly = ye ? 0.f : (y - y0f);
          float lx = xe ? 0.f : (x - x0f);
          float hy = 1.f - ly, hx = 1.f - lx;
          atomicAdd(&acc[y0 * 16 + x0], hy * hx);
          atomicAdd(&acc[y0 * 16 + x1i], hy * lx);
          atomicAdd(&acc[y1i * 16 + x0], ly * hx);
          atomicAdd(&acc[y1i * 16 + x1i], ly * lx);
        }
      }
    }
    __syncthreads();
    wbar[n * 256 + tid] = acc[tid] * (1.f / 1024.f);
  }
}

// ---------------------------------------------------------------------------
// K3: GEMM  Y[o][col] = sum_c Wb[o][c] * FpT[col][c], M=1024 N=4096 K=2048.
// BM=128 BN=64 BK=64, 4 waves (2x2), gld_lds(16B) pre-swizzled src.
// 512 blocks = 2/CU. Epilogue: bf16 Y (halves tail traffic; R9-validated
// numerically) + f32 GN partial sums from unrounded acc.
// ---------------------------------------------------------------------------
__global__ __launch_bounds__(256) void gemm_kernel(
    const __hip_bfloat16* __restrict__ Wb,   // [1024][2048]
    const __hip_bfloat16* __restrict__ FpT,  // [4096][2048]
    __hip_bfloat16* __restrict__ Yb,         // [1024][4096] bf16
    float2* __restrict__ partials)           // [128 groups][16 slots]
{
  __shared__ unsigned short lA[128 * 64];
  __shared__ unsigned short lB[64 * 64];
  const int tid = threadIdx.x;
  const int lane = tid & 63;
  const int wid = tid >> 6;
  const int wm = wid >> 1, wn = wid & 1;
  const int nb = blockIdx.x, mb = blockIdx.y;
  const int lr8 = lane >> 3;
  const int lk  = lane & 7;

  f32x4 acc[4][2] = {};

  for (int k0 = 0; k0 < 2048; k0 += 64) {
    __syncthreads();
    #pragma unroll
    for (int j = 0; j < 4; ++j) {
      int row = wid * 32 + j * 8 + lr8;
      int kslot = lk ^ (row & 7);
      const __hip_bfloat16* g = Wb + (size_t)(mb * 128 + row) * 2048 + k0 + kslot * 8;
      gld_lds16(&lA[(wid * 32 + j * 8) * 64], g);
    }
    #pragma unroll
    for (int j = 0; j < 2; ++j) {
      int row = wid * 16 + j * 8 + lr8;
      int kslot = lk ^ (row & 7);
      const __hip_bfloat16* g = FpT + (size_t)(nb * 64 + row) * 2048 + k0 + kslot * 8;
      gld_lds16(&lB[(wid * 16 + j * 8) * 64], g);
    }
    __syncthreads();

    #pragma unroll
    for (int s = 0; s < 2; ++s) {
      s16x8 af[4], bf[2];
      #pragma unroll
      for (int mi = 0; mi < 4; ++mi) {
        int row = wm * 64 + mi * 16 + (lane & 15);
        int kslot = (s * 4 + (lane >> 4)) ^ (row & 7);
        af[mi] = *(const s16x8*)((const char*)lA + (row << 7) + (kslot << 4));
      }
      #pragma unroll
      for (int ni = 0; ni < 2; ++ni) {
        int row = wn * 32 + ni * 16 + (lane & 15);
        int kslot = (s * 4 + (lane >> 4)) ^ (row & 7);
        bf[ni] = *(const s16x8*)((const char*)lB + (row << 7) + (kslot << 4));
      }
      #pragma unroll
      for (int mi = 0; mi < 4; ++mi)
        #pragma unroll
        for (int ni = 0; ni < 2; ++ni)
          acc[mi][ni] = __builtin_amdgcn_mfma_f32_16x16x32_bf16(af[mi], bf[ni], acc[mi][ni], 0, 0, 0);
    }
  }

  // C-write: C/D mapping col=lane&15, row=(lane>>4)*4+reg (m89/m91-verified)
  float s = 0.f, ss = 0.f;
  #pragma unroll
  for (int mi = 0; mi < 4; ++mi) {
    #pragma unroll
    for (int ni = 0; ni < 2; ++ni) {
      int col = nb * 64 + wn * 32 + ni * 16 + (lane & 15);
      int o0 = mb * 128 + wm * 64 + mi * 16 + (lane >> 4) * 4;
      #pragma unroll
      for (int r = 0; r < 4; ++r) {
        float v = acc[mi][ni][r];
        Yb[(size_t)(o0 + r) * 4096 + col] = __float2bfloat16(v);
        s += v;
        ss += v * v;
      }
    }
  }
  #pragma unroll
  for (int off = 32; off; off >>= 1) {
    s += __shfl_xor(s, off);
    ss += __shfl_xor(ss, off);
  }
  if (lane == 0) {
    int b = nb >> 3;
    int g = 2 * mb + wm;
    partials[(b * 16 + g) * 16 + (nb & 7) * 2 + wn] = make_float2(s, ss);
  }
}

// ---------------------------------------------------------------------------
// K4 (fused): GroupNorm normalize + ReLU + (c t)-interleave feat store, PLUS
// roi_feat/roi_pos column reductions (each block exclusively owns its 8 feat
// channels -> direct stores, no atomics, deterministic).
// grid 2048 = ((b*16+g)*16 + q), 256 thr. Each wave: one o-channel, both t
// halves (32 lanes x 8 wh each); roi reduce via width-32 shfl_xor.
// ---------------------------------------------------------------------------
__global__ __launch_bounds__(256) void gn_roi_kernel(
    const __hip_bfloat16* __restrict__ Yb, const float2* __restrict__ partials,
    const float* __restrict__ gamma, const float* __restrict__ beta,
    const float* __restrict__ pos, const float* __restrict__ wbar,
    float* __restrict__ out)
{
  __shared__ float wl[16][256];
  int blk = blockIdx.x;
  int q = blk & 15;
  int bg = blk >> 4;            // b*16 + g
  int b = bg >> 4, g = bg & 15;
  int tid = threadIdx.x;
  #pragma unroll
  for (int n = 0; n < 16; ++n)
    wl[n][tid] = wbar[(b * 16 + n) * 256 + tid];
  __syncthreads();

  const float2* pp = partials + bg * 16;
  float S = 0.f, SS = 0.f;
  #pragma unroll
  for (int j = 0; j < 16; ++j) { float2 v = pp[j]; S += v.x; SS += v.y; }
  float mu = S * (1.f / 32768.f);
  float var = SS * (1.f / 32768.f) - mu * mu;
  float rstd = rsqrtf(var + 1e-5f);

  int o_l = q * 4 + (tid >> 6);
  int o = g * 64 + o_l;
  int lane = tid & 63;
  int colpos = lane * 8;        // within the 512 cols of batch b
  int t = colpos >> 8;          // lane >= 32
  int wh0 = colpos & 255;
  int c = o * 2 + t;            // feat channel
  float ga = gamma[o] * rstd, be = beta[o] - mu * rstd * gamma[o];

  s16x8 yv = *(const s16x8*)(Yb + (size_t)o * 4096 + b * 512 + colpos);
  float f[8];
  #pragma unroll
  for (int j = 0; j < 8; ++j)
    f[j] = fmaxf(__uint_as_float((unsigned)(unsigned short)yv[j] << 16) * ga + be, 0.f);

  float* dst = out + ((size_t)(b * 2048 + c)) * 256 + wh0;
  *(float4*)dst = make_float4(f[0], f[1], f[2], f[3]);
  *(float4*)(dst + 4) = make_float4(f[4], f[5], f[6], f[7]);

  float4 p0 = *(const float4*)(pos + (size_t)c * 256 + wh0);
  float4 p1 = *(const float4*)(pos + (size_t)c * 256 + wh0 + 4);

  #pragma unroll
  for (int n = 0; n < 16; ++n) {
    float4 w0 = *(const float4*)&wl[n][wh0];
    float4 w1 = *(const float4*)&wl[n][wh0 + 4];
    float aF = w0.x * f[0] + w0.y * f[1] + w0.z * f[2] + w0.w * f[3]
             + w1.x * f[4] + w1.y * f[5] + w1.z * f[6] + w1.w * f[7];
    float aP = w0.x * p0.x + w0.y * p0.y + w0.z * p0.z + w0.w * p0.w
             + w1.x * p1.x + w1.y * p1.y + w1.z * p1.z + w1.w * p1.w;
    #pragma unroll
    for (int off = 1; off < 32; off <<= 1) {
      aF += __shfl_xor(aF, off, 32);
      aP += __shfl_xor(aP, off, 32);
    }
    if ((lane & 31) == 0) {
      out[FEATSZ + (size_t)(b * 16 + n) * 2048 + c] = aF;
      out[FEATSZ + ROISZ + (size_t)(b * 16 + n) * 2048 + c] = aP;
    }
  }
}

// ---------------------------------------------------------------------------
extern "C" void kernel_launch(void* const* d_in, const int* in_sizes, int n_in,
                              void* d_out, int out_size, void* d_ws, size_t ws_size,
                              hipStream_t stream)
{
  (void)in_sizes; (void)n_in; (void)out_size; (void)ws_size;
  const float* slow   = (const float*)d_in[0];
  const float* fast   = (const float*)d_in[1];
  const float* rois   = (const float*)d_in[2];
  const float* pos    = (const float*)d_in[3];
  const float* conv_w = (const float*)d_in[4];
  const float* gamma  = (const float*)d_in[5];
  const float* beta   = (const float*)d_in[6];
  float* out = (float*)d_out;
  char* ws = (char*)d_ws;

  // Workspace (~28.15 MB):
  //   [0, 16M)        FpT [4096][2048] bf16
  //   [16M, 24M)      Yb  [1024][4096] bf16
  //   [24M, 28M)      Wb  [1024][2048] bf16
  //   [28M, +128K)    wbar [128][256] f32
  //   [28M+128K,+16K) partials [128][16] float2
  __hip_bfloat16* FpT = (__hip_bfloat16*)(ws);
  __hip_bfloat16* Yb  = (__hip_bfloat16*)(ws + (16u << 20));
  __hip_bfloat16* Wb  = (__hip_bfloat16*)(ws + (24u << 20));
  float* wbar         = (float*)(ws + (28u << 20));
  float2* partials    = (float2*)(ws + (28u << 20) + (128u << 10));

  fused_pre_kernel<<<dim3(704), dim3(256), 0, stream>>>(
      slow, fast, conv_w, rois, FpT, Wb, wbar);
  gemm_kernel<<<dim3(64, 8), dim3(256), 0, stream>>>(Wb, FpT, Yb, partials);
  gn_roi_kernel<<<dim3(2048), dim3(256), 0, stream>>>(
      Yb, partials, gamma, beta, pos, wbar, out);
}